// Round 2
// baseline (183.452 us; speedup 1.0000x reference)
//
#include <hip/hip_runtime.h>
#include <stdint.h>

#define B_   16
#define N_   100
#define D_   1024
#define L_   2000
#define M_   1600      // B_*N_
#define KP   2048      // padded label-dim (hist region width)
#define AK   3072      // Acat / B0cat row stride (feature|hist , wcat0|biasBT)

#define RCAP 24
#define DCAP 32        // max dirty columns (a-rows) per batch; E[#] ~= 5
#define ZMAX 2400
#define TC   6         // task chunk in k_mix (typ. ntask = ndv+1 ~ 6 -> one pass)

typedef __bf16 bf16x8 __attribute__((ext_vector_type(8)));
typedef float  f32x4  __attribute__((ext_vector_type(4)));

__device__ __forceinline__ void gl_lds16(const __bf16* g, __bf16* l) {
    __builtin_amdgcn_global_load_lds(
        (const __attribute__((address_space(1))) void*)g,
        (__attribute__((address_space(3))) void*)l, 16, 0, 0);
}

// ---------------- prep: cvt (feature, weights) + bias transpose + graph histogram ----------
// Acat  [1600][3072] bf16 : cols [0,1024) = feature, cols [1024,3072) = label histogram
// B0cat [1024][3072] bf16 : cols [0,1024) = (W0+W1) rows, cols [1024,3072) = bias^T
// wcat12[2048][1024] bf16 : Wa rows then Wb rows
// colZ  [16][100] int     : per-batch per-COLUMN zero counts (for dirty-col GEMM)

__global__ void __launch_bounds__(256)
k_prep(const float* __restrict__ f,
       const float* __restrict__ W0, const float* __restrict__ W1,
       const float* __restrict__ Wa, const float* __restrict__ Wb,
       const float* __restrict__ bias, const int* __restrict__ graph,
       __bf16* __restrict__ Acat, __bf16* __restrict__ B0cat,
       __bf16* __restrict__ wcat12, int* __restrict__ colZ) {
    int bid = blockIdx.x, t = threadIdx.x;
    __shared__ float lds[32][33];
    __shared__ unsigned int hist[KP];

    if (bid < 2336) {
        int i = bid * 256 + t;               // < 598016 exactly
        union { __bf16 h[8]; uint4 u; } pk;
        if (i < 204800) {                    // feature cvt -> Acat[:, 0:1024)
            long base = (long)i * 8;
            const float4* p = (const float4*)(f + base);
            float4 x = p[0], y = p[1];
            pk.h[0]=(__bf16)x.x; pk.h[1]=(__bf16)x.y; pk.h[2]=(__bf16)x.z; pk.h[3]=(__bf16)x.w;
            pk.h[4]=(__bf16)y.x; pk.h[5]=(__bf16)y.y; pk.h[6]=(__bf16)y.z; pk.h[7]=(__bf16)y.w;
            int m = i >> 7, c = i & 127;     // 128 uint4 of feature per row
            ((uint4*)Acat)[(long)m * 384 + c] = pk.u;
        } else {
            int j = i - 204800;              // < 393216 (3 x 1024x1024 / 8)
            long base = (long)j * 8;
            long seg = base >> 20;
            int  js  = j & 131071;           // index within segment (uint4 units)
            if (seg == 0) {                  // W0+W1 -> B0cat[:, 0:1024)
                long off = (long)js * 8;
                const float4* p0 = (const float4*)(W0 + off);
                const float4* p1 = (const float4*)(W1 + off);
                float4 a0 = p0[0], a1 = p0[1], b0 = p1[0], b1 = p1[1];
                pk.h[0]=(__bf16)(a0.x+b0.x); pk.h[1]=(__bf16)(a0.y+b0.y);
                pk.h[2]=(__bf16)(a0.z+b0.z); pk.h[3]=(__bf16)(a0.w+b0.w);
                pk.h[4]=(__bf16)(a1.x+b1.x); pk.h[5]=(__bf16)(a1.y+b1.y);
                pk.h[6]=(__bf16)(a1.z+b1.z); pk.h[7]=(__bf16)(a1.w+b1.w);
                int row = js >> 7, c = js & 127;
                ((uint4*)B0cat)[(long)row * 384 + c] = pk.u;
            } else {                         // Wa / Wb -> wcat12 (contiguous)
                const float* src = (seg == 1) ? Wa : Wb;
                long off = (long)js * 8;
                const float4* p = (const float4*)(src + off);
                float4 x = p[0], y = p[1];
                pk.h[0]=(__bf16)x.x; pk.h[1]=(__bf16)x.y; pk.h[2]=(__bf16)x.z; pk.h[3]=(__bf16)x.w;
                pk.h[4]=(__bf16)y.x; pk.h[5]=(__bf16)y.y; pk.h[6]=(__bf16)y.z; pk.h[7]=(__bf16)y.w;
                ((uint4*)wcat12)[(long)(seg - 1) * 131072 + js] = pk.u;
            }
        }
    } else if (bid < 4384) {                 // bias transpose -> B0cat[:, 1024:3072)
        int tb = bid - 2336;                 // 2048 blocks: lt<64, dt<32
        int lt = tb >> 5, dt = tb & 31;
        int l0 = lt * 32, d0 = dt * 32;
        int r = t >> 3, cq = (t & 7) * 4;
        float4 v = make_float4(0.f, 0.f, 0.f, 0.f);
        if (l0 + r < L_) v = *(const float4*)(bias + (long)(l0 + r) * D_ + d0 + cq);
        lds[r][cq]=v.x; lds[r][cq+1]=v.y; lds[r][cq+2]=v.z; lds[r][cq+3]=v.w;
        __syncthreads();
        union { __bf16 h[4]; uint2 u; } pk;
        #pragma unroll
        for (int q = 0; q < 4; ++q) pk.h[q] = (__bf16)lds[cq + q][r];
        *(uint2*)(B0cat + (long)(d0 + r) * AK + 1024 + l0 + cq) = pk.u;
    } else {
        int m = bid - 4384;                  // 1600 blocks: per-row label histogram
        for (int k = t; k < KP; k += 256) hist[k] = 0u;
        __syncthreads();
        if (t < N_) {
            int gv = graph[(long)m * N_ + t];
            atomicAdd(&hist[gv], 1u);
            if (gv == 0) atomicAdd(&colZ[(m / N_) * N_ + t], 1);  // column t has a zero in row m
        }
        __syncthreads();
        union { __bf16 h[8]; uint4 u; } pk;
        #pragma unroll
        for (int q = 0; q < 8; ++q) pk.h[q] = (__bf16)(float)hist[t * 8 + q];
        ((uint4*)(Acat + (long)m * AK + 1024))[t] = pk.u;
        // note: Acat[m][1024] == zero-count of row m (exact in bf16 for counts<=256)
    }
}

// -------- merged GEMM dispatch (LPT: long K=3072 merged blocks FIRST) --------
// blocks [0,200):   out0 [1600x1024] = Acat @ B0cat^T  (K=3072, 48 iters)  + feat
// blocks [200,400): bB   [1600x1024] = Acat[:,:1024] @ Wb^T (K=1024, 16 iters) + bbias
// blocks [400,464): aD   [512x1024]  = dirty-col feature rows @ Wa^T + ba (16 iters)
// XCD-affine: bn = pid&7 -> each XCD's resident blocks share ONE B-panel (L2-resident).

#define BM 64
#define BN 128
#define BK 64

__global__ void __launch_bounds__(256)
k_gemmAll(const __bf16* __restrict__ Acat, const __bf16* __restrict__ B0cat,
          const __bf16* __restrict__ wcat12, const int* __restrict__ colZ,
          const float* __restrict__ feat, const float* __restrict__ ba,
          const float* __restrict__ bbias,
          float* __restrict__ out0, float* __restrict__ bB, float* __restrict__ aD) {
    __shared__ __align__(16) __bf16 As[BM * BK];   // 8 KB
    __shared__ __align__(16) __bf16 Bs[BN * BK];   // 16 KB
    __shared__ int czL[2 * N_];
    __shared__ int dcolL[2][DCAP];
    int t = threadIdx.x;
    int pid = blockIdx.x;
    int lane = t & 63, wave = t >> 6;
    int wr = wave & 1, wc = wave >> 1;
    int lrow = lane & 15, quad = lane >> 4;

    int kind = (pid < 200) ? 0 : (pid < 400 ? 1 : 2);   // 0 merged, 1 bB, 2 aD
    int bm, bn, K;
    long ldb;
    const __bf16 *Bg;
    if (kind == 0) {
        bn = pid & 7; bm = pid >> 3;               // bm in [0,25)
        Bg = B0cat + (long)(bn * BN) * AK;
        ldb = AK; K = AK;
    } else if (kind == 1) {
        int p2 = pid - 200;
        bn = p2 & 7; bm = p2 >> 3;                 // bm in [0,25)
        Bg = wcat12 + (long)(1024 + bn * BN) * 1024;   // Wb panel
        ldb = 1024; K = 1024;
    } else {
        int p3 = pid - 400;
        bn = p3 & 7; bm = p3 >> 3;                 // bm in [0,8): batches 2bm,2bm+1
        Bg = wcat12 + (long)(bn * BN) * 1024;          // Wa panel
        ldb = 1024; K = 1024;
        // build deterministic ascending dirty-col lists for the 2 covered batches
        if (t < 2 * N_) czL[t] = colZ[bm * 2 * N_ + t];
        __syncthreads();
        if (t < 2) {
            int rank = 0;
            for (int j = 0; j < N_; ++j)
                if (czL[t * N_ + j] > 0 && rank < DCAP) dcolL[t][rank++] = j;
            for (; rank < DCAP; ++rank) dcolL[t][rank] = 0;
        }
        __syncthreads();
    }

    // per-thread staging source pointers (A rows r0,r1; B rows rb0..rb3)
    int r0 = t >> 3, r1 = 32 + (t >> 3);
    int c0 = (t & 7) ^ (r0 & 7), c1 = (t & 7) ^ (r1 & 7);
    const __bf16 *aS0, *aS1;
    if (kind == 2) {
        int b0g = bm * 2 + (r0 >> 5), s0 = r0 & 31;
        int b1g = bm * 2 + (r1 >> 5), s1 = r1 & 31;
        aS0 = Acat + (long)(b0g * N_ + dcolL[r0 >> 5][s0]) * AK + c0 * 8;
        aS1 = Acat + (long)(b1g * N_ + dcolL[r1 >> 5][s1]) * AK + c1 * 8;
    } else {
        aS0 = Acat + (long)(bm * BM + r0) * AK + c0 * 8;
        aS1 = Acat + (long)(bm * BM + r1) * AK + c1 * 8;
    }
    const __bf16 *bS[4];
    #pragma unroll
    for (int pi = 0; pi < 4; ++pi) {
        int rb = pi * 32 + (t >> 3), cb = (t & 7) ^ (rb & 7);
        bS[pi] = Bg + (long)rb * ldb + cb * 8;
    }

    f32x4 acc[2][4] = {};
    for (int k0 = 0; k0 < K; k0 += BK) {
        gl_lds16(aS0 + k0, As + t * 8);
        gl_lds16(aS1 + k0, As + (256 + t) * 8);
        #pragma unroll
        for (int pi = 0; pi < 4; ++pi)
            gl_lds16(bS[pi] + k0, Bs + (pi * 256 + t) * 8);
        __syncthreads();
        #pragma unroll
        for (int ks = 0; ks < 2; ++ks) {
            bf16x8 af[2], bf[4];
            #pragma unroll
            for (int i = 0; i < 2; ++i) {
                int r = wr * 32 + i * 16 + lrow;
                int slot = r * 8 + (((ks << 2) | quad) ^ (r & 7));
                af[i] = *(const bf16x8*)(As + slot * 8);
            }
            #pragma unroll
            for (int j = 0; j < 4; ++j) {
                int r = wc * 64 + j * 16 + lrow;
                int slot = r * 8 + (((ks << 2) | quad) ^ (r & 7));
                bf[j] = *(const bf16x8*)(Bs + slot * 8);
            }
            #pragma unroll
            for (int i = 0; i < 2; ++i)
                #pragma unroll
                for (int j = 0; j < 4; ++j)
                    acc[i][j] = __builtin_amdgcn_mfma_f32_16x16x32_bf16(af[i], bf[j], acc[i][j], 0, 0, 0);
        }
        __syncthreads();
    }

    #pragma unroll
    for (int i = 0; i < 2; ++i) {
        int gm0 = bm * BM + wr * 32 + i * 16 + quad * 4;
        #pragma unroll
        for (int j = 0; j < 4; ++j) {
            int col = bn * BN + wc * 64 + j * 16 + lrow;          // < 1024
            #pragma unroll
            for (int r = 0; r < 4; ++r) {
                long m = gm0 + r;
                float v = acc[i][j][r];
                if (kind == 0)      out0[m * D_ + col] = v + feat[m * D_ + col];
                else if (kind == 1) bB[m * D_ + col]   = v + bbias[col];
                else                aD[m * D_ + col]   = v + ba[col];
            }
        }
    }
}

// ---------------- alpha: deterministic self-scan + corr -> per-column weights ----------------
// block pid -> (b, kc): 4 columns k = kc*4+{0..3}. Dirty rows ranked by increasing row index.
// Row zero counts from the prep histogram; dirty-col a-rows from the compacted aD GEMM.

__global__ void __launch_bounds__(256)
k_alpha(const int* __restrict__ graph, const __bf16* __restrict__ Acat,
        const int* __restrict__ colZ, const float* __restrict__ aD,
        const float* __restrict__ bB, float* __restrict__ wl, float* __restrict__ cwG) {
    __shared__ int rowCnt[N_], rowOff[N_], rowRank[N_];
    __shared__ int czA[N_], colSlotL[N_];
    __shared__ int ndvS, totZS;
    __shared__ int zjL[ZMAX];
    __shared__ short prL[ZMAX];
    __shared__ float corrL[RCAP][4];
    __shared__ float wred[4][4];

    int pid = blockIdx.x;                    // 0..399
    int b = pid / 25, kc = pid - b * 25;
    int t = threadIdx.x, lane = t & 63, wave = t >> 6;

    const int* g = graph + (long)b * N_ * N_;
    if (t < N_) {
        rowCnt[t] = (int)(float)Acat[(long)(b * N_ + t) * AK + 1024];
        czA[t] = colZ[b * N_ + t];
    }
    if (t < RCAP * 4) corrL[t >> 2][t & 3] = 0.f;
    __syncthreads();
    if (t == 0) {
        int off = 0, rank = 0;
        for (int i = 0; i < N_; ++i) {
            if (rowCnt[i] > 0 && rank < RCAP) {
                rowRank[i] = rank; rowOff[i] = off; off += rowCnt[i]; ++rank;
            } else rowRank[i] = -1;
        }
        ndvS = rank; totZS = off;
    }
    if (t == 64) {                           // wave 1: dirty-col slot map (same order as GEMM)
        int ds = 0;
        for (int j = 0; j < N_; ++j) {
            if (czA[j] > 0) { colSlotL[j] = (ds < DCAP) ? ds : 0; ++ds; }
            else colSlotL[j] = -1;
        }
    }
    __syncthreads();
    if (t < N_ && rowRank[t] >= 0) {
        int pos = rowOff[t], r = rowRank[t];
        for (int j = 0; j < N_; ++j)
            if (g[t * N_ + j] == 0) { zjL[pos] = j; prL[pos] = (short)r; ++pos; }
    }
    __syncthreads();
    int Z = totZS, ndv = ndvS;

    int k0 = kc * 4;
    float4 bv[4];
    #pragma unroll
    for (int kk = 0; kk < 4; ++kk)
        bv[kk] = *(const float4*)(bB + ((long)(b * N_ + k0 + kk)) * D_ + t * 4);

    for (int q = 0; q < Z; ++q) {
        int slot = colSlotL[zjL[q]];
        const float* ar = aD + ((long)(b * DCAP + slot)) * D_;
        float4 av = *(const float4*)(ar + t * 4);
        float s[4];
        #pragma unroll
        for (int kk = 0; kk < 4; ++kk)
            s[kk] = av.x * bv[kk].x + av.y * bv[kk].y + av.z * bv[kk].z + av.w * bv[kk].w;
        #pragma unroll
        for (int off = 32; off > 0; off >>= 1)
            #pragma unroll
            for (int kk = 0; kk < 4; ++kk) s[kk] += __shfl_xor(s[kk], off);
        if (lane == 0) { wred[wave][0]=s[0]; wred[wave][1]=s[1]; wred[wave][2]=s[2]; wred[wave][3]=s[3]; }
        __syncthreads();
        if (t < 4) {
            float v = wred[0][t] + wred[1][t] + wred[2][t] + wred[3][t];
            corrL[prL[q]][t] += fmaxf(v, 0.f);
        }
        __syncthreads();
    }

    if (t < 4) {
        int k = k0 + t;
        float denom = (float)(N_ - ndv);
        for (int r = 0; r < ndv; ++r) {
            float e = __expf(-corrL[r][t]);
            corrL[r][t] = e;
            denom += e;
        }
        float w = 1.f / denom;
        wl[b * N_ + k] = w;
        for (int r = 0; r < ndv; ++r)
            cwG[((long)b * RCAP + r) * N_ + k] = corrL[r][t] * w;
    }
}

// ---------------- mix: out rows = weighted sums of out0 rows (float4) -----------
// grid (16, 8): 128 f32 cols per block, 8 j-groups (stride-8 rows, 12-13 serial iters).

__global__ void __launch_bounds__(256)
k_mix(const __bf16* __restrict__ Acat, const float* __restrict__ wl,
      const float* __restrict__ cwG, const float* __restrict__ out0,
      float* __restrict__ out) {
    int b = blockIdx.x, dq = blockIdx.y;     // dq < 8
    int t = threadIdx.x, c4 = t & 31, q = t >> 5;
    int d0 = dq * 128;
    __shared__ int hasZ[N_], mapL[N_], ndvS;
    __shared__ float wT[TC][N_];
    __shared__ f32x4 parts[8][TC][32];       // 24 KB

    if (t < N_)
        hasZ[t] = ((float)Acat[(long)(b * N_ + t) * AK + 1024] > 0.f) ? 1 : 0;
    __syncthreads();
    if (t < N_) {
        int rank = 0;
        for (int i = 0; i < t; ++i) rank += hasZ[i];
        mapL[t] = (hasZ[t] && rank < RCAP) ? 1 + rank : 0;
    }
    if (t == 0) {
        int n = 0;
        for (int i = 0; i < N_; ++i) n += hasZ[i];
        ndvS = min(n, RCAP);
    }
    __syncthreads();
    int ndv = ndvS, ntask = ndv + 1;

    const float* o0 = out0 + (long)b * N_ * D_ + d0;
    for (int cb = 0; cb < ntask; cb += TC) {
        for (int idx = t; idx < TC * N_; idx += 256) {
            int rr = idx / N_, j = idx - rr * N_;
            int task = cb + rr;
            float v = 0.f;
            if (task == 0)         v = wl[b * N_ + j];
            else if (task <= ndv)  v = cwG[((long)b * RCAP + task - 1) * N_ + j];
            wT[rr][j] = v;
        }
        __syncthreads();
        f32x4 acc[TC] = {};
        for (int j = q; j < N_; j += 8) {
            f32x4 v = *(const f32x4*)(o0 + (long)j * D_ + c4 * 4);
            #pragma unroll
            for (int rr = 0; rr < TC; ++rr) acc[rr] += wT[rr][j] * v;
        }
        #pragma unroll
        for (int rr = 0; rr < TC; ++rr) parts[q][rr][c4] = acc[rr];
        __syncthreads();
        for (int i = q; i < N_; i += 8) {
            int task = mapL[i];
            if (task >= cb && task < cb + TC) {
                int rr = task - cb;
                f32x4 s = parts[0][rr][c4];
                #pragma unroll
                for (int p = 1; p < 8; ++p) s += parts[p][rr][c4];
                *(f32x4*)(out + ((long)(b * N_ + i)) * D_ + d0 + c4 * 4) = s;
            }
        }
        __syncthreads();
    }
}

// ---------------- launch ----------------

extern "C" void kernel_launch(void* const* d_in, const int* in_sizes, int n_in,
                              void* d_out, int out_size, void* d_ws, size_t ws_size,
                              hipStream_t stream) {
    const float* feature = (const float*)d_in[0];
    const int*   graph   = (const int*)d_in[1];
    const float* W0      = (const float*)d_in[2];
    const float* W1      = (const float*)d_in[3];
    const float* bias    = (const float*)d_in[4];
    const float* dp_Wa   = (const float*)d_in[5];
    const float* dp_ba   = (const float*)d_in[6];
    const float* dp_Wb   = (const float*)d_in[7];
    const float* dp_bb   = (const float*)d_in[8];
    float* out = (float*)d_out;

    char* w = (char*)d_ws;
    __bf16* Acat   = (__bf16*)(w);                   // 1600*3072*2 =  9,830,400
    __bf16* B0cat  = (__bf16*)(w + 9830400);         // 1024*3072*2 =  6,291,456
    __bf16* wcat12 = (__bf16*)(w + 16121856);        // 2048*1024*2 =  4,194,304
    float*  out0   = (float*)(w + 20316160);         // 6,553,600
    float*  bB     = (float*)(w + 26869760);         // 6,553,600
    float*  aD     = (float*)(w + 33423360);         // 512*1024*4  =  2,097,152
    float*  wl     = (float*)(w + 35520512);         // 6,400
    float*  cwG    = (float*)(w + 35526912);         // 153,600
    int*    colZ   = (int*)  (w + 35680512);         // 6,400 (end 35,686,912)

    hipMemsetAsync(colZ, 0, B_ * N_ * sizeof(int), stream);
    k_prep<<<5984, 256, 0, stream>>>(feature, W0, W1, dp_Wa, dp_Wb, bias, graph,
                                     Acat, B0cat, wcat12, colZ);
    k_gemmAll<<<464, 256, 0, stream>>>(Acat, B0cat, wcat12, colZ, feature, dp_ba, dp_bb,
                                       out0, bB, aD);
    k_alpha<<<400, 256, 0, stream>>>(graph, Acat, colZ, aD, bB, wl, cwG);
    k_mix<<<dim3(B_, 8), 256, 0, stream>>>(Acat, wl, cwG, out0, out);
}

// Round 3
// 163.349 us; speedup vs baseline: 1.1231x; 1.1231x over previous
//
#include <hip/hip_runtime.h>
#include <stdint.h>

#define B_   16
#define N_   100
#define D_   1024
#define L_   2000
#define M_   1600      // B_*N_
#define KP   2048      // padded label-dim (hist region width)
#define AK   3072      // Acat / B0cat row stride (feature|hist , wcat0|biasBT)

#define RCAP 24
#define DCAP 32        // max dirty columns (a-rows) per batch; E[#] ~= 5
#define ZMAX 2400
#define TC   6         // task chunk in k_mix (typ. ntask = ndv+1 ~ 6 -> one pass)

typedef __bf16 bf16x8 __attribute__((ext_vector_type(8)));
typedef float  f32x4  __attribute__((ext_vector_type(4)));

__device__ __forceinline__ void gl_lds16(const __bf16* g, __bf16* l) {
    __builtin_amdgcn_global_load_lds(
        (const __attribute__((address_space(1))) void*)g,
        (__attribute__((address_space(3))) void*)l, 16, 0, 0);
}

// ---------------- prep: cvt (feature, weights) + bias transpose + histogram + colZ ----------
// Acat  [1600][3072] bf16 : cols [0,1024) = feature, cols [1024,3072) = label histogram
// B0cat [1024][3072] bf16 : cols [0,1024) = (W0+W1) rows, cols [1024,3072) = bias^T
// wcat12[2048][1024] bf16 : Wa rows then Wb rows
// colZ  [16][100] int     : per-batch per-COLUMN zero counts (for dirty-col GEMM)

__global__ void __launch_bounds__(256)
k_prep(const float* __restrict__ f,
       const float* __restrict__ W0, const float* __restrict__ W1,
       const float* __restrict__ Wa, const float* __restrict__ Wb,
       const float* __restrict__ bias, const int* __restrict__ graph,
       __bf16* __restrict__ Acat, __bf16* __restrict__ B0cat,
       __bf16* __restrict__ wcat12, int* __restrict__ colZ) {
    int bid = blockIdx.x, t = threadIdx.x;
    __shared__ float lds[32][33];
    __shared__ unsigned int hist[KP];

    if (bid < 2336) {
        int i = bid * 256 + t;               // < 598016 exactly
        union { __bf16 h[8]; uint4 u; } pk;
        if (i < 204800) {                    // feature cvt -> Acat[:, 0:1024)
            long base = (long)i * 8;
            const float4* p = (const float4*)(f + base);
            float4 x = p[0], y = p[1];
            pk.h[0]=(__bf16)x.x; pk.h[1]=(__bf16)x.y; pk.h[2]=(__bf16)x.z; pk.h[3]=(__bf16)x.w;
            pk.h[4]=(__bf16)y.x; pk.h[5]=(__bf16)y.y; pk.h[6]=(__bf16)y.z; pk.h[7]=(__bf16)y.w;
            int m = i >> 7, c = i & 127;     // 128 uint4 of feature per row
            ((uint4*)Acat)[(long)m * 384 + c] = pk.u;
        } else {
            int j = i - 204800;              // < 393216 (3 x 1024x1024 / 8)
            long base = (long)j * 8;
            long seg = base >> 20;
            int  js  = j & 131071;           // index within segment (uint4 units)
            if (seg == 0) {                  // W0+W1 -> B0cat[:, 0:1024)
                long off = (long)js * 8;
                const float4* p0 = (const float4*)(W0 + off);
                const float4* p1 = (const float4*)(W1 + off);
                float4 a0 = p0[0], a1 = p0[1], b0 = p1[0], b1 = p1[1];
                pk.h[0]=(__bf16)(a0.x+b0.x); pk.h[1]=(__bf16)(a0.y+b0.y);
                pk.h[2]=(__bf16)(a0.z+b0.z); pk.h[3]=(__bf16)(a0.w+b0.w);
                pk.h[4]=(__bf16)(a1.x+b1.x); pk.h[5]=(__bf16)(a1.y+b1.y);
                pk.h[6]=(__bf16)(a1.z+b1.z); pk.h[7]=(__bf16)(a1.w+b1.w);
                int row = js >> 7, c = js & 127;
                ((uint4*)B0cat)[(long)row * 384 + c] = pk.u;
            } else {                         // Wa / Wb -> wcat12 (contiguous)
                const float* src = (seg == 1) ? Wa : Wb;
                long off = (long)js * 8;
                const float4* p = (const float4*)(src + off);
                float4 x = p[0], y = p[1];
                pk.h[0]=(__bf16)x.x; pk.h[1]=(__bf16)x.y; pk.h[2]=(__bf16)x.z; pk.h[3]=(__bf16)x.w;
                pk.h[4]=(__bf16)y.x; pk.h[5]=(__bf16)y.y; pk.h[6]=(__bf16)y.z; pk.h[7]=(__bf16)y.w;
                ((uint4*)wcat12)[(long)(seg - 1) * 131072 + js] = pk.u;
            }
        }
    } else if (bid < 4384) {                 // bias transpose -> B0cat[:, 1024:3072)
        int tb = bid - 2336;                 // 2048 blocks: lt<64, dt<32
        int lt = tb >> 5, dt = tb & 31;
        int l0 = lt * 32, d0 = dt * 32;
        int r = t >> 3, cq = (t & 7) * 4;
        float4 v = make_float4(0.f, 0.f, 0.f, 0.f);
        if (l0 + r < L_) v = *(const float4*)(bias + (long)(l0 + r) * D_ + d0 + cq);
        lds[r][cq]=v.x; lds[r][cq+1]=v.y; lds[r][cq+2]=v.z; lds[r][cq+3]=v.w;
        __syncthreads();
        union { __bf16 h[4]; uint2 u; } pk;
        #pragma unroll
        for (int q = 0; q < 4; ++q) pk.h[q] = (__bf16)lds[cq + q][r];
        *(uint2*)(B0cat + (long)(d0 + r) * AK + 1024 + l0 + cq) = pk.u;
    } else if (bid < 5984) {
        int m = bid - 4384;                  // 1600 blocks: per-row label histogram
        for (int k = t; k < KP; k += 256) hist[k] = 0u;
        __syncthreads();
        if (t < N_) atomicAdd(&hist[graph[(long)m * N_ + t]], 1u);
        __syncthreads();
        union { __bf16 h[8]; uint4 u; } pk;
        #pragma unroll
        for (int q = 0; q < 8; ++q) pk.h[q] = (__bf16)(float)hist[t * 8 + q];
        ((uint4*)(Acat + (long)m * AK + 1024))[t] = pk.u;
        // note: Acat[m][1024] == zero-count of row m (exact in bf16 for counts<=256)
    } else {
        int b = bid - 5984;                  // 16 blocks: per-batch column zero counts
        if (t < N_) {
            const int* g = graph + (long)b * N_ * N_;
            int c = 0;
            for (int i = 0; i < N_; ++i) c += (g[i * N_ + t] == 0);
            colZ[b * N_ + t] = c;
        }
    }
}

// -------- merged GEMM dispatch: 864 UNIFORM 16-iter blocks (split-K, no long pole) --------
// blocks [0,600):   out0/out0b/out0c [1600x1024] = Acat[:,kc] @ B0cat[:,kc]^T, kc = chunk*1024
//                   chunk 0 adds feat; chunks 1,2 write raw partials (summed in k_mix)
// blocks [600,800): bB [1600x1024] = Acat[:,:1024] @ Wb^T + bbias (16 iters)
// blocks [800,864): aD [512x1024]  = dirty-col feature rows @ Wa^T + ba (16 iters)
// A-affine XCD mapping: p&7 = XCD; each XCD keeps ~3 A panels (1.2 MB) L2-resident across
// all chunks + bB (offsets 0/200/400/600/800 are multiples of 8 -> p&7 == pid&7).

#define BM 64
#define BN 128
#define BK 64

__global__ void __launch_bounds__(256)
k_gemmAll(const __bf16* __restrict__ Acat, const __bf16* __restrict__ B0cat,
          const __bf16* __restrict__ wcat12, const int* __restrict__ colZ,
          const float* __restrict__ feat, const float* __restrict__ ba,
          const float* __restrict__ bbias,
          float* __restrict__ out0, float* __restrict__ out0b, float* __restrict__ out0c,
          float* __restrict__ bB, float* __restrict__ aD) {
    __shared__ __align__(16) __bf16 As[BM * BK];   // 8 KB
    __shared__ __align__(16) __bf16 Bs[BN * BK];   // 16 KB
    __shared__ int czL[2 * N_];
    __shared__ int dcolL[2][DCAP];
    int t = threadIdx.x;
    int pid = blockIdx.x;
    int lane = t & 63, wave = t >> 6;
    int wr = wave & 1, wc = wave >> 1;
    int lrow = lane & 15, quad = lane >> 4;

    int kind, chunk = 0, bm, bn;
    long ldb, koff = 0;
    const __bf16 *Bg;
    if (pid < 600) {
        kind = 0; chunk = pid / 200;
        int p = pid - chunk * 200;
        int v = (p & 7) * 25 + (p >> 3);           // [0,200) unique
        bm = v >> 3; bn = v & 7;                   // per-XCD: bm ~3 contiguous
        koff = (long)chunk * 1024;
        Bg = B0cat + (long)(bn * BN) * AK + koff;
        ldb = AK;
    } else if (pid < 800) {
        kind = 1;
        int p = pid - 600;
        int v = (p & 7) * 25 + (p >> 3);
        bm = v >> 3; bn = v & 7;
        Bg = wcat12 + (long)(1024 + bn * BN) * 1024;   // Wb panel
        ldb = 1024;
    } else {
        kind = 2;
        int p = pid - 800;
        bn = p & 7; bm = p >> 3;                   // bm in [0,8): batches 2bm,2bm+1
        Bg = wcat12 + (long)(bn * BN) * 1024;          // Wa panel
        ldb = 1024;
        // deterministic ascending dirty-col lists for the 2 covered batches
        if (t < 2 * N_) czL[t] = colZ[bm * 2 * N_ + t];
        __syncthreads();
        if (t < 2) {
            int rank = 0;
            for (int j = 0; j < N_; ++j)
                if (czL[t * N_ + j] > 0 && rank < DCAP) dcolL[t][rank++] = j;
            for (; rank < DCAP; ++rank) dcolL[t][rank] = 0;
        }
        __syncthreads();
    }

    // per-thread staging source pointers (A rows r0,r1; B rows rb0..rb3)
    int r0 = t >> 3, r1 = 32 + (t >> 3);
    int c0 = (t & 7) ^ (r0 & 7), c1 = (t & 7) ^ (r1 & 7);
    const __bf16 *aS0, *aS1;
    if (kind == 2) {
        int b0g = bm * 2 + (r0 >> 5), s0 = r0 & 31;
        int b1g = bm * 2 + (r1 >> 5), s1 = r1 & 31;
        aS0 = Acat + (long)(b0g * N_ + dcolL[r0 >> 5][s0]) * AK + c0 * 8;
        aS1 = Acat + (long)(b1g * N_ + dcolL[r1 >> 5][s1]) * AK + c1 * 8;
    } else {
        aS0 = Acat + (long)(bm * BM + r0) * AK + koff + c0 * 8;
        aS1 = Acat + (long)(bm * BM + r1) * AK + koff + c1 * 8;
    }
    const __bf16 *bS[4];
    #pragma unroll
    for (int pi = 0; pi < 4; ++pi) {
        int rb = pi * 32 + (t >> 3), cb = (t & 7) ^ (rb & 7);
        bS[pi] = Bg + (long)rb * ldb + cb * 8;
    }

    f32x4 acc[2][4] = {};
    for (int k0 = 0; k0 < 1024; k0 += BK) {
        gl_lds16(aS0 + k0, As + t * 8);
        gl_lds16(aS1 + k0, As + (256 + t) * 8);
        #pragma unroll
        for (int pi = 0; pi < 4; ++pi)
            gl_lds16(bS[pi] + k0, Bs + (pi * 256 + t) * 8);
        __syncthreads();
        #pragma unroll
        for (int ks = 0; ks < 2; ++ks) {
            bf16x8 af[2], bf[4];
            #pragma unroll
            for (int i = 0; i < 2; ++i) {
                int r = wr * 32 + i * 16 + lrow;
                int slot = r * 8 + (((ks << 2) | quad) ^ (r & 7));
                af[i] = *(const bf16x8*)(As + slot * 8);
            }
            #pragma unroll
            for (int j = 0; j < 4; ++j) {
                int r = wc * 64 + j * 16 + lrow;
                int slot = r * 8 + (((ks << 2) | quad) ^ (r & 7));
                bf[j] = *(const bf16x8*)(Bs + slot * 8);
            }
            #pragma unroll
            for (int i = 0; i < 2; ++i)
                #pragma unroll
                for (int j = 0; j < 4; ++j)
                    acc[i][j] = __builtin_amdgcn_mfma_f32_16x16x32_bf16(af[i], bf[j], acc[i][j], 0, 0, 0);
        }
        __syncthreads();
    }

    #pragma unroll
    for (int i = 0; i < 2; ++i) {
        int gm0 = bm * BM + wr * 32 + i * 16 + quad * 4;
        #pragma unroll
        for (int j = 0; j < 4; ++j) {
            int col = bn * BN + wc * 64 + j * 16 + lrow;          // < 1024
            #pragma unroll
            for (int r = 0; r < 4; ++r) {
                long m = gm0 + r;
                float v = acc[i][j][r];
                if (kind == 0) {
                    if (chunk == 0)      out0[m * D_ + col]  = v + feat[m * D_ + col];
                    else if (chunk == 1) out0b[m * D_ + col] = v;
                    else                 out0c[m * D_ + col] = v;
                } else if (kind == 1) bB[m * D_ + col] = v + bbias[col];
                else                  aD[m * D_ + col] = v + ba[col];
            }
        }
    }
}

// ---------------- alpha: deterministic self-scan + corr -> per-column weights ----------------
// block pid -> (b, kc): 4 columns k = kc*4+{0..3}. Dirty rows ranked by increasing row index.
// Row zero counts from the prep histogram; dirty-col a-rows from the compacted aD GEMM.

__global__ void __launch_bounds__(256)
k_alpha(const int* __restrict__ graph, const __bf16* __restrict__ Acat,
        const int* __restrict__ colZ, const float* __restrict__ aD,
        const float* __restrict__ bB, float* __restrict__ wl, float* __restrict__ cwG) {
    __shared__ int rowCnt[N_], rowOff[N_], rowRank[N_];
    __shared__ int czA[N_], colSlotL[N_];
    __shared__ int ndvS, totZS;
    __shared__ int zjL[ZMAX];
    __shared__ short prL[ZMAX];
    __shared__ float corrL[RCAP][4];
    __shared__ float wred[4][4];

    int pid = blockIdx.x;                    // 0..399
    int b = pid / 25, kc = pid - b * 25;
    int t = threadIdx.x, lane = t & 63, wave = t >> 6;

    const int* g = graph + (long)b * N_ * N_;
    if (t < N_) {
        rowCnt[t] = (int)(float)Acat[(long)(b * N_ + t) * AK + 1024];
        czA[t] = colZ[b * N_ + t];
    }
    if (t < RCAP * 4) corrL[t >> 2][t & 3] = 0.f;
    __syncthreads();
    if (t == 0) {
        int off = 0, rank = 0;
        for (int i = 0; i < N_; ++i) {
            if (rowCnt[i] > 0 && rank < RCAP) {
                rowRank[i] = rank; rowOff[i] = off; off += rowCnt[i]; ++rank;
            } else rowRank[i] = -1;
        }
        ndvS = rank; totZS = off;
    }
    if (t == 64) {                           // wave 1: dirty-col slot map (same order as GEMM)
        int ds = 0;
        for (int j = 0; j < N_; ++j) {
            if (czA[j] > 0) { colSlotL[j] = (ds < DCAP) ? ds : 0; ++ds; }
            else colSlotL[j] = -1;
        }
    }
    __syncthreads();
    if (t < N_ && rowRank[t] >= 0) {
        int pos = rowOff[t], r = rowRank[t];
        for (int j = 0; j < N_; ++j)
            if (g[t * N_ + j] == 0) { zjL[pos] = j; prL[pos] = (short)r; ++pos; }
    }
    __syncthreads();
    int Z = totZS, ndv = ndvS;

    int k0 = kc * 4;
    float4 bv[4];
    #pragma unroll
    for (int kk = 0; kk < 4; ++kk)
        bv[kk] = *(const float4*)(bB + ((long)(b * N_ + k0 + kk)) * D_ + t * 4);

    for (int q = 0; q < Z; ++q) {
        int slot = colSlotL[zjL[q]];
        const float* ar = aD + ((long)(b * DCAP + slot)) * D_;
        float4 av = *(const float4*)(ar + t * 4);
        float s[4];
        #pragma unroll
        for (int kk = 0; kk < 4; ++kk)
            s[kk] = av.x * bv[kk].x + av.y * bv[kk].y + av.z * bv[kk].z + av.w * bv[kk].w;
        #pragma unroll
        for (int off = 32; off > 0; off >>= 1)
            #pragma unroll
            for (int kk = 0; kk < 4; ++kk) s[kk] += __shfl_xor(s[kk], off);
        if (lane == 0) { wred[wave][0]=s[0]; wred[wave][1]=s[1]; wred[wave][2]=s[2]; wred[wave][3]=s[3]; }
        __syncthreads();
        if (t < 4) {
            float v = wred[0][t] + wred[1][t] + wred[2][t] + wred[3][t];
            corrL[prL[q]][t] += fmaxf(v, 0.f);
        }
        __syncthreads();
    }

    if (t < 4) {
        int k = k0 + t;
        float denom = (float)(N_ - ndv);
        for (int r = 0; r < ndv; ++r) {
            float e = __expf(-corrL[r][t]);
            corrL[r][t] = e;
            denom += e;
        }
        float w = 1.f / denom;
        wl[b * N_ + k] = w;
        for (int r = 0; r < ndv; ++r)
            cwG[((long)b * RCAP + r) * N_ + k] = corrL[r][t] * w;
    }
}

// ---------------- mix: out rows = weighted sums of (out0+out0b+out0c) rows -----------
// grid (16, 16): 64 f32 cols per block, 16 j-groups (stride-16 rows, 6-7 serial iters).

__global__ void __launch_bounds__(256)
k_mix(const __bf16* __restrict__ Acat, const float* __restrict__ wl,
      const float* __restrict__ cwG, const float* __restrict__ out0,
      const float* __restrict__ out0b, const float* __restrict__ out0c,
      float* __restrict__ out) {
    int b = blockIdx.x, dq = blockIdx.y;     // dq < 16
    int t = threadIdx.x, c4 = t & 15, q = t >> 4;
    int d0 = dq * 64;
    __shared__ int hasZ[N_], mapL[N_], ndvS;
    __shared__ float wT[TC][N_];
    __shared__ f32x4 parts[16][TC][16];      // 24 KB

    if (t < N_)
        hasZ[t] = ((float)Acat[(long)(b * N_ + t) * AK + 1024] > 0.f) ? 1 : 0;
    __syncthreads();
    if (t < N_) {
        int rank = 0;
        for (int i = 0; i < t; ++i) rank += hasZ[i];
        mapL[t] = (hasZ[t] && rank < RCAP) ? 1 + rank : 0;
    }
    if (t == 0) {
        int n = 0;
        for (int i = 0; i < N_; ++i) n += hasZ[i];
        ndvS = min(n, RCAP);
    }
    __syncthreads();
    int ndv = ndvS, ntask = ndv + 1;

    const float* o0 = out0  + (long)b * N_ * D_ + d0;
    const float* ob = out0b + (long)b * N_ * D_ + d0;
    const float* oc = out0c + (long)b * N_ * D_ + d0;
    for (int cb = 0; cb < ntask; cb += TC) {
        for (int idx = t; idx < TC * N_; idx += 256) {
            int rr = idx / N_, j = idx - rr * N_;
            int task = cb + rr;
            float v = 0.f;
            if (task == 0)         v = wl[b * N_ + j];
            else if (task <= ndv)  v = cwG[((long)b * RCAP + task - 1) * N_ + j];
            wT[rr][j] = v;
        }
        __syncthreads();
        f32x4 acc[TC] = {};
        for (int j = q; j < N_; j += 16) {
            f32x4 v = *(const f32x4*)(o0 + (long)j * D_ + c4 * 4)
                    + *(const f32x4*)(ob + (long)j * D_ + c4 * 4)
                    + *(const f32x4*)(oc + (long)j * D_ + c4 * 4);
            #pragma unroll
            for (int rr = 0; rr < TC; ++rr) acc[rr] += wT[rr][j] * v;
        }
        #pragma unroll
        for (int rr = 0; rr < TC; ++rr) parts[q][rr][c4] = acc[rr];
        __syncthreads();
        for (int i = q; i < N_; i += 16) {
            int task = mapL[i];
            if (task >= cb && task < cb + TC) {
                int rr = task - cb;
                f32x4 s = parts[0][rr][c4];
                #pragma unroll
                for (int p = 1; p < 16; ++p) s += parts[p][rr][c4];
                *(f32x4*)(out + ((long)(b * N_ + i)) * D_ + d0 + c4 * 4) = s;
            }
        }
        __syncthreads();
    }
}

// ---------------- launch ----------------

extern "C" void kernel_launch(void* const* d_in, const int* in_sizes, int n_in,
                              void* d_out, int out_size, void* d_ws, size_t ws_size,
                              hipStream_t stream) {
    const float* feature = (const float*)d_in[0];
    const int*   graph   = (const int*)d_in[1];
    const float* W0      = (const float*)d_in[2];
    const float* W1      = (const float*)d_in[3];
    const float* bias    = (const float*)d_in[4];
    const float* dp_Wa   = (const float*)d_in[5];
    const float* dp_ba   = (const float*)d_in[6];
    const float* dp_Wb   = (const float*)d_in[7];
    const float* dp_bb   = (const float*)d_in[8];
    float* out = (float*)d_out;

    char* w = (char*)d_ws;
    __bf16* Acat   = (__bf16*)(w);                   // 1600*3072*2 =  9,830,400
    __bf16* B0cat  = (__bf16*)(w + 9830400);         // 1024*3072*2 =  6,291,456
    __bf16* wcat12 = (__bf16*)(w + 16121856);        // 2048*1024*2 =  4,194,304
    float*  out0   = (float*)(w + 20316160);         // 6,553,600
    float*  out0b  = (float*)(w + 26869760);         // 6,553,600
    float*  out0c  = (float*)(w + 33423360);         // 6,553,600
    float*  bB     = (float*)(w + 39976960);         // 6,553,600
    float*  aD     = (float*)(w + 46530560);         // 512*1024*4  =  2,097,152
    float*  wl     = (float*)(w + 48627712);         // 6,400
    float*  cwG    = (float*)(w + 48634112);         // 153,600
    int*    colZ   = (int*)  (w + 48787712);         // 6,400 (end 48,794,112)

    k_prep<<<6000, 256, 0, stream>>>(feature, W0, W1, dp_Wa, dp_Wb, bias, graph,
                                     Acat, B0cat, wcat12, colZ);
    k_gemmAll<<<864, 256, 0, stream>>>(Acat, B0cat, wcat12, colZ, feature, dp_ba, dp_bb,
                                       out0, out0b, out0c, bB, aD);
    k_alpha<<<400, 256, 0, stream>>>(graph, Acat, colZ, aD, bB, wl, cwG);
    k_mix<<<dim3(B_, 16), 256, 0, stream>>>(Acat, wl, cwG, out0, out0b, out0c, out);
}